// Round 1
// baseline (192.431 us; speedup 1.0000x reference)
//
#include <hip/hip_runtime.h>

#define DEV __device__ __forceinline__

typedef __bf16 bf16x8 __attribute__((ext_vector_type(8)));
typedef unsigned short u16x8v __attribute__((ext_vector_type(8)));
typedef float f32x4 __attribute__((ext_vector_type(4)));
typedef unsigned short u16;
typedef unsigned int u32;

// f32 -> bf16 bits, round-to-nearest-even
DEV u16 f2bf(float f) {
    u32 u = __builtin_bit_cast(u32, f);
    u = (u + 0x7FFFu + ((u >> 16) & 1u)) >> 16;
    return (u16)u;
}

DEV bf16x8 ld_bf8(const u16* p) {
    return *reinterpret_cast<const bf16x8*>(p);
}

// ---------------------------------------------------------------------------
// Kernel 1: transpose+convert weights.  W[c][h] f32 (512x64) -> Wt[w][h][c] bf16
// ---------------------------------------------------------------------------
__global__ __launch_bounds__(256) void wconv_kernel(const float* __restrict__ W0,
                                                    const float* __restrict__ W1,
                                                    const float* __restrict__ W2,
                                                    u16* __restrict__ Wt) {
    int idx = blockIdx.x * 256 + threadIdx.x;   // 3*64*512 = 98304 total
    if (idx >= 3 * 64 * 512) return;
    int w = idx >> 15;          // / 32768
    int rem = idx & 32767;
    int h = rem >> 9;           // / 512
    int c = rem & 511;
    const float* W = (w == 0) ? W0 : ((w == 1) ? W1 : W2);
    Wt[idx] = f2bf(W[c * 64 + h]);
}

// ---------------------------------------------------------------------------
// Kernel 2: fused QKV projection via MFMA 16x16x32 bf16.
// M = 16384 rows (B*T), K = 512, N = 3*64.
// Block: 256 threads = 4 waves; each wave owns 16 rows, all 192 out cols.
// Writes Q,K as [row][64] bf16; V transposed as Vt[b][h][t] bf16.
// MFMA layouts (verified on gfx950):
//   A: lane holds A[lane&15][8*(lane>>4)+j]
//   B: lane holds B[8*(lane>>4)+j][lane&15]
//   D: lane holds D[4*(lane>>4)+reg][lane&15]
// ---------------------------------------------------------------------------
__global__ __launch_bounds__(256) void proj_kernel(const float* __restrict__ x,
                                                   const u16* __restrict__ Wt,
                                                   u16* __restrict__ Q,
                                                   u16* __restrict__ Kq,
                                                   u16* __restrict__ Vt) {
    const int wave = threadIdx.x >> 6, lane = threadIdx.x & 63;
    const int lr = lane & 15, lg = lane >> 4;
    const int r0 = blockIdx.x * 64 + wave * 16;
    const int grow = r0 + lr;

    f32x4 acc[3][4];
#pragma unroll
    for (int a = 0; a < 3; ++a)
#pragma unroll
        for (int b = 0; b < 4; ++b) acc[a][b] = (f32x4){0.f, 0.f, 0.f, 0.f};

#pragma unroll
    for (int kk = 0; kk < 16; ++kk) {
        const float* xp = x + (size_t)grow * 512 + kk * 32 + lg * 8;
        float4 a0 = *reinterpret_cast<const float4*>(xp);
        float4 a1 = *reinterpret_cast<const float4*>(xp + 4);
        u16x8v ub;
        ub[0] = f2bf(a0.x); ub[1] = f2bf(a0.y); ub[2] = f2bf(a0.z); ub[3] = f2bf(a0.w);
        ub[4] = f2bf(a1.x); ub[5] = f2bf(a1.y); ub[6] = f2bf(a1.z); ub[7] = f2bf(a1.w);
        bf16x8 af = __builtin_bit_cast(bf16x8, ub);
#pragma unroll
        for (int w3 = 0; w3 < 3; ++w3) {
#pragma unroll
            for (int nt = 0; nt < 4; ++nt) {
                bf16x8 bf = ld_bf8(Wt + w3 * 32768 + (lr + 16 * nt) * 512 + kk * 32 + lg * 8);
                acc[w3][nt] = __builtin_amdgcn_mfma_f32_16x16x32_bf16(af, bf, acc[w3][nt], 0, 0, 0);
            }
        }
    }

    const int bidx = r0 >> 12;            // batch (T=4096 rows per batch)
    const int t0 = (r0 & 4095) + 4 * lg;  // V-transpose row start
#pragma unroll
    for (int nt = 0; nt < 4; ++nt) {
        const int h = lr + 16 * nt;
#pragma unroll
        for (int reg = 0; reg < 4; ++reg) {
            const int gr2 = r0 + 4 * lg + reg;
            Q[(size_t)gr2 * 64 + h]  = f2bf(acc[0][nt][reg]);
            Kq[(size_t)gr2 * 64 + h] = f2bf(acc[1][nt][reg]);
        }
        ushort4 hv;
        hv.x = f2bf(acc[2][nt][0]); hv.y = f2bf(acc[2][nt][1]);
        hv.z = f2bf(acc[2][nt][2]); hv.w = f2bf(acc[2][nt][3]);
        *reinterpret_cast<ushort4*>(Vt + ((size_t)(bidx * 64 + h)) * 4096 + t0) = hv;
    }
}

// ---------------------------------------------------------------------------
// Kernel 3: causal flash attention.
// 1024 independent waves; each owns 16 q-rows; iterates 64-key tiles.
// Q,K: [b][t][64] bf16.  Vt: [b][h][t] bf16.  out: [b][t][64] f32.
// ---------------------------------------------------------------------------
__global__ __launch_bounds__(256) void attn_kernel(const u16* __restrict__ Q,
                                                   const u16* __restrict__ K,
                                                   const u16* __restrict__ Vt,
                                                   float* __restrict__ out) {
    __shared__ __align__(16) u16 P_lds[4][16][72];   // per-wave, padded rows (144B)
    const int wave = threadIdx.x >> 6, lane = threadIdx.x & 63;
    const int lr = lane & 15, lg = lane >> 4;
    const int ti = blockIdx.x * 4 + wave;    // 0..1023 q-tiles of 16 rows
    const int b = ti >> 8, qi = ti & 255;
    const int qr0 = qi * 16;

    const u16* Qb = Q + (size_t)b * 4096 * 64;
    const u16* Kb = K + (size_t)b * 4096 * 64;
    const u16* Vb = Vt + (size_t)b * 64 * 4096;

    bf16x8 aq[2];
#pragma unroll
    for (int kk = 0; kk < 2; ++kk)
        aq[kk] = ld_bf8(Qb + (size_t)(qr0 + lr) * 64 + kk * 32 + lg * 8);

    f32x4 o[4];
#pragma unroll
    for (int ht = 0; ht < 4; ++ht) o[ht] = (f32x4){0.f, 0.f, 0.f, 0.f};
    float m_run[4], l_run[4];
#pragma unroll
    for (int reg = 0; reg < 4; ++reg) { m_run[reg] = -3.0e38f; l_run[reg] = 0.f; }

    const int nkv = qr0 / 64 + 1;
    const float SCL = 0.044194173824159216f;   // 1/sqrt(512)
    const float L2E = 1.4426950408889634f;

    for (int it = 0; it < nkv; ++it) {
        const int kv0 = it * 64;
        f32x4 s[4];
#pragma unroll
        for (int nt = 0; nt < 4; ++nt) s[nt] = (f32x4){0.f, 0.f, 0.f, 0.f};

        // S = Q K^T  (16 x 64 per wave)
#pragma unroll
        for (int nt = 0; nt < 4; ++nt) {
#pragma unroll
            for (int kk = 0; kk < 2; ++kk) {
                bf16x8 bk = ld_bf8(Kb + (size_t)(kv0 + 16 * nt + lr) * 64 + kk * 32 + lg * 8);
                s[nt] = __builtin_amdgcn_mfma_f32_16x16x32_bf16(aq[kk], bk, s[nt], 0, 0, 0);
            }
        }

        // scale + causal mask + row max
        float pm[4];
#pragma unroll
        for (int reg = 0; reg < 4; ++reg) pm[reg] = -3.0e38f;
#pragma unroll
        for (int nt = 0; nt < 4; ++nt) {
            const int kglob = kv0 + 16 * nt + lr;
#pragma unroll
            for (int reg = 0; reg < 4; ++reg) {
                const int qglob = qr0 + 4 * lg + reg;
                float v = s[nt][reg] * SCL;
                v = (kglob <= qglob) ? v : -3.0e38f;
                s[nt][reg] = v;
                pm[reg] = fmaxf(pm[reg], v);
            }
        }
#pragma unroll
        for (int reg = 0; reg < 4; ++reg) {
#pragma unroll
            for (int off = 1; off < 16; off <<= 1)
                pm[reg] = fmaxf(pm[reg], __shfl_xor(pm[reg], off, 64));
        }

        float al[4];
#pragma unroll
        for (int reg = 0; reg < 4; ++reg) {
            float mn = fmaxf(m_run[reg], pm[reg]);
            al[reg] = exp2f((m_run[reg] - mn) * L2E);
            m_run[reg] = mn;
        }

        float rs[4] = {0.f, 0.f, 0.f, 0.f};
#pragma unroll
        for (int nt = 0; nt < 4; ++nt) {
#pragma unroll
            for (int reg = 0; reg < 4; ++reg) {
                float p = exp2f((s[nt][reg] - m_run[reg]) * L2E);
                s[nt][reg] = p;
                rs[reg] += p;
            }
        }
#pragma unroll
        for (int reg = 0; reg < 4; ++reg) {
#pragma unroll
            for (int off = 1; off < 16; off <<= 1)
                rs[reg] += __shfl_xor(rs[reg], off, 64);
            l_run[reg] = l_run[reg] * al[reg] + rs[reg];
        }
#pragma unroll
        for (int ht = 0; ht < 4; ++ht)
#pragma unroll
            for (int reg = 0; reg < 4; ++reg) o[ht][reg] *= al[reg];

        // P -> LDS (per-wave private region; wave-internal transpose)
#pragma unroll
        for (int nt = 0; nt < 4; ++nt)
#pragma unroll
            for (int reg = 0; reg < 4; ++reg)
                P_lds[wave][4 * lg + reg][lr + 16 * nt] = f2bf(s[nt][reg]);

        __asm__ volatile("s_waitcnt lgkmcnt(0)" ::: "memory");
        __builtin_amdgcn_sched_barrier(0);

        bf16x8 ap[2];
#pragma unroll
        for (int kk = 0; kk < 2; ++kk)
            ap[kk] = *reinterpret_cast<const bf16x8*>(&P_lds[wave][lr][kk * 32 + lg * 8]);

        // O += P V   (B-operand from transposed V: contiguous loads)
#pragma unroll
        for (int ht = 0; ht < 4; ++ht) {
#pragma unroll
            for (int kk = 0; kk < 2; ++kk) {
                bf16x8 bv = ld_bf8(Vb + (size_t)(lr + 16 * ht) * 4096 + kv0 + kk * 32 + lg * 8);
                o[ht] = __builtin_amdgcn_mfma_f32_16x16x32_bf16(ap[kk], bv, o[ht], 0, 0, 0);
            }
        }
        __asm__ volatile("" ::: "memory");
    }

    // normalize + store f32 out[b][t][64]
#pragma unroll
    for (int reg = 0; reg < 4; ++reg) l_run[reg] = 1.0f / l_run[reg];
#pragma unroll
    for (int ht = 0; ht < 4; ++ht)
#pragma unroll
        for (int reg = 0; reg < 4; ++reg)
            out[(size_t)(b * 4096 + qr0 + 4 * lg + reg) * 64 + lr + 16 * ht] =
                o[ht][reg] * l_run[reg];
}

// ---------------------------------------------------------------------------
extern "C" void kernel_launch(void* const* d_in, const int* in_sizes, int n_in,
                              void* d_out, int out_size, void* d_ws, size_t ws_size,
                              hipStream_t stream) {
    const float* x  = (const float*)d_in[0];
    const float* Wq = (const float*)d_in[1];
    const float* Wk = (const float*)d_in[2];
    const float* Wv = (const float*)d_in[3];
    float* out = (float*)d_out;

    char* ws = (char*)d_ws;
    u16* Qw  = (u16*)(ws);                       // 16384*64 bf16 = 2 MiB
    u16* Kw  = (u16*)(ws + (size_t)2 * 1024 * 1024);
    u16* Vtw = (u16*)(ws + (size_t)4 * 1024 * 1024);
    u16* Wt  = (u16*)(ws + (size_t)6 * 1024 * 1024);   // 3*64*512 bf16

    wconv_kernel<<<384, 256, 0, stream>>>(Wq, Wk, Wv, Wt);
    proj_kernel<<<256, 256, 0, stream>>>(x, Wt, Qw, Kw, Vtw);
    attn_kernel<<<256, 256, 0, stream>>>(Qw, Kw, Vtw, out);
}

// Round 2
// 146.471 us; speedup vs baseline: 1.3138x; 1.3138x over previous
//
#include <hip/hip_runtime.h>

#define DEV __device__ __forceinline__

typedef __bf16 bf16x8 __attribute__((ext_vector_type(8)));
typedef unsigned short u16x8v __attribute__((ext_vector_type(8)));
typedef float f32x4 __attribute__((ext_vector_type(4)));
typedef unsigned short u16;
typedef unsigned int u32;

// f32 -> bf16 bits, round-to-nearest-even
DEV u16 f2bf(float f) {
    u32 u = __builtin_bit_cast(u32, f);
    u = (u + 0x7FFFu + ((u >> 16) & 1u)) >> 16;
    return (u16)u;
}

DEV bf16x8 ld_bf8(const u16* p) {
    return *reinterpret_cast<const bf16x8*>(p);
}

// ---------------------------------------------------------------------------
// Kernel 1: transpose+convert weights.  W[c][h] f32 (512x64) -> Wt[w][h][c] bf16
// ---------------------------------------------------------------------------
__global__ __launch_bounds__(256) void wconv_kernel(const float* __restrict__ W0,
                                                    const float* __restrict__ W1,
                                                    const float* __restrict__ W2,
                                                    u16* __restrict__ Wt) {
    int idx = blockIdx.x * 256 + threadIdx.x;   // 3*64*512 = 98304 total
    if (idx >= 3 * 64 * 512) return;
    int w = idx >> 15;
    int rem = idx & 32767;
    int h = rem >> 9;
    int c = rem & 511;
    const float* W = (w == 0) ? W0 : ((w == 1) ? W1 : W2);
    Wt[idx] = f2bf(W[c * 64 + h]);
}

// ---------------------------------------------------------------------------
// Kernel 2: QKV projection via MFMA 16x16x32 bf16.
// 768 blocks: mat = blk%3 (Q/K/V), rowgroup = blk/3.  Wave: 16 rows x 64 cols.
// 3072 waves total (12/CU).  Q,K row-major bf16; V transposed Vt[b][h][t] bf16.
// MFMA layouts (gfx950): A: lane holds A[lane&15][8*(lane>>4)+j]
//                        B: lane holds B[8*(lane>>4)+j][lane&15]
//                        D: lane holds D[4*(lane>>4)+reg][lane&15]
// ---------------------------------------------------------------------------
__global__ __launch_bounds__(256) void proj_kernel(const float* __restrict__ x,
                                                   const u16* __restrict__ Wt,
                                                   u16* __restrict__ Q,
                                                   u16* __restrict__ Kq,
                                                   u16* __restrict__ Vt) {
    const int wave = threadIdx.x >> 6, lane = threadIdx.x & 63;
    const int lr = lane & 15, lg = lane >> 4;
    const int mat = blockIdx.x % 3;
    const int rg = blockIdx.x / 3;
    const int r0 = rg * 64 + wave * 16;
    const int grow = r0 + lr;

    f32x4 acc[4];
#pragma unroll
    for (int b = 0; b < 4; ++b) acc[b] = (f32x4){0.f, 0.f, 0.f, 0.f};

#pragma unroll
    for (int kk = 0; kk < 16; ++kk) {
        const float* xp = x + (size_t)grow * 512 + kk * 32 + lg * 8;
        float4 a0 = *reinterpret_cast<const float4*>(xp);
        float4 a1 = *reinterpret_cast<const float4*>(xp + 4);
        u16x8v ub;
        ub[0] = f2bf(a0.x); ub[1] = f2bf(a0.y); ub[2] = f2bf(a0.z); ub[3] = f2bf(a0.w);
        ub[4] = f2bf(a1.x); ub[5] = f2bf(a1.y); ub[6] = f2bf(a1.z); ub[7] = f2bf(a1.w);
        bf16x8 af = __builtin_bit_cast(bf16x8, ub);
#pragma unroll
        for (int nt = 0; nt < 4; ++nt) {
            bf16x8 bf = ld_bf8(Wt + mat * 32768 + (lr + 16 * nt) * 512 + kk * 32 + lg * 8);
            acc[nt] = __builtin_amdgcn_mfma_f32_16x16x32_bf16(af, bf, acc[nt], 0, 0, 0);
        }
    }

    if (mat < 2) {
        u16* dst = (mat == 0) ? Q : Kq;
#pragma unroll
        for (int nt = 0; nt < 4; ++nt) {
            const int h = lr + 16 * nt;
#pragma unroll
            for (int reg = 0; reg < 4; ++reg)
                dst[(size_t)(r0 + 4 * lg + reg) * 64 + h] = f2bf(acc[nt][reg]);
        }
    } else {
        const int bidx = r0 >> 12;
        const int t0 = (r0 & 4095) + 4 * lg;
#pragma unroll
        for (int nt = 0; nt < 4; ++nt) {
            const int h = lr + 16 * nt;
            ushort4 hv;
            hv.x = f2bf(acc[nt][0]); hv.y = f2bf(acc[nt][1]);
            hv.z = f2bf(acc[nt][2]); hv.w = f2bf(acc[nt][3]);
            *reinterpret_cast<ushort4*>(Vt + ((size_t)(bidx * 64 + h)) * 4096 + t0) = hv;
        }
    }
}

// ---------------------------------------------------------------------------
// Kernel 3: causal flash attention, KV-split partials.
// gid = blk*4+wave in [0, 1024*SPLIT): ti = gid & 1023 (q-tile), c = gid >> 10.
// Wave computes partial (O,m,l) over kv-tiles [c*CT, min(nkv,(c+1)*CT)).
// If FINAL (SPLIT==1): normalize and write f32 out directly.
// ---------------------------------------------------------------------------
__global__ __launch_bounds__(256) void attn_part_kernel(const u16* __restrict__ Q,
                                                        const u16* __restrict__ K,
                                                        const u16* __restrict__ Vt,
                                                        float* __restrict__ Opart,
                                                        float* __restrict__ Mpart,
                                                        float* __restrict__ Lpart,
                                                        float* __restrict__ out,
                                                        int SPLIT, int CT, int final_out) {
    __shared__ __align__(16) u16 P_lds[4][16][72];   // per-wave, padded rows
    const int wave = threadIdx.x >> 6, lane = threadIdx.x & 63;
    const int lr = lane & 15, lg = lane >> 4;
    const int gid = blockIdx.x * 4 + wave;
    const int ti = gid & 1023;
    const int c = gid >> 10;
    const int b = ti >> 8, qi = ti & 255;
    const int qr0 = qi * 16;
    const int nkv = (qi >> 2) + 1;               // kv-tiles of 64 for this q-tile
    const int it0 = c * CT;
    if (it0 >= nkv) return;
    const int it1 = min(nkv, it0 + CT);

    const u16* Qb = Q + (size_t)b * 4096 * 64;
    const u16* Kb = K + (size_t)b * 4096 * 64;
    const u16* Vb = Vt + (size_t)b * 64 * 4096;

    bf16x8 aq[2];
#pragma unroll
    for (int kk = 0; kk < 2; ++kk)
        aq[kk] = ld_bf8(Qb + (size_t)(qr0 + lr) * 64 + kk * 32 + lg * 8);

    f32x4 o[4];
#pragma unroll
    for (int ht = 0; ht < 4; ++ht) o[ht] = (f32x4){0.f, 0.f, 0.f, 0.f};
    float m_run[4], l_run[4];
#pragma unroll
    for (int reg = 0; reg < 4; ++reg) { m_run[reg] = -3.0e38f; l_run[reg] = 0.f; }

    const float SCL = 0.044194173824159216f;   // 1/sqrt(512)
    const float L2E = 1.4426950408889634f;

    for (int it = it0; it < it1; ++it) {
        const int kv0 = it * 64;
        f32x4 s[4];
#pragma unroll
        for (int nt = 0; nt < 4; ++nt) s[nt] = (f32x4){0.f, 0.f, 0.f, 0.f};

        // S = Q K^T  (16 x 64 per wave)
#pragma unroll
        for (int nt = 0; nt < 4; ++nt) {
#pragma unroll
            for (int kk = 0; kk < 2; ++kk) {
                bf16x8 bk = ld_bf8(Kb + (size_t)(kv0 + 16 * nt + lr) * 64 + kk * 32 + lg * 8);
                s[nt] = __builtin_amdgcn_mfma_f32_16x16x32_bf16(aq[kk], bk, s[nt], 0, 0, 0);
            }
        }

        // scale + causal mask + row max
        float pm[4];
#pragma unroll
        for (int reg = 0; reg < 4; ++reg) pm[reg] = -3.0e38f;
#pragma unroll
        for (int nt = 0; nt < 4; ++nt) {
            const int kglob = kv0 + 16 * nt + lr;
#pragma unroll
            for (int reg = 0; reg < 4; ++reg) {
                const int qglob = qr0 + 4 * lg + reg;
                float v = s[nt][reg] * SCL;
                v = (kglob <= qglob) ? v : -3.0e38f;
                s[nt][reg] = v;
                pm[reg] = fmaxf(pm[reg], v);
            }
        }
#pragma unroll
        for (int reg = 0; reg < 4; ++reg) {
#pragma unroll
            for (int off = 1; off < 16; off <<= 1)
                pm[reg] = fmaxf(pm[reg], __shfl_xor(pm[reg], off, 64));
        }

        float al[4];
#pragma unroll
        for (int reg = 0; reg < 4; ++reg) {
            float mn = fmaxf(m_run[reg], pm[reg]);
            al[reg] = exp2f((m_run[reg] - mn) * L2E);
            m_run[reg] = mn;
        }

        float rs[4] = {0.f, 0.f, 0.f, 0.f};
#pragma unroll
        for (int nt = 0; nt < 4; ++nt) {
#pragma unroll
            for (int reg = 0; reg < 4; ++reg) {
                float p = exp2f((s[nt][reg] - m_run[reg]) * L2E);
                s[nt][reg] = p;
                rs[reg] += p;
            }
        }
#pragma unroll
        for (int reg = 0; reg < 4; ++reg) {
#pragma unroll
            for (int off = 1; off < 16; off <<= 1)
                rs[reg] += __shfl_xor(rs[reg], off, 64);
            l_run[reg] = l_run[reg] * al[reg] + rs[reg];
        }
#pragma unroll
        for (int ht = 0; ht < 4; ++ht)
#pragma unroll
            for (int reg = 0; reg < 4; ++reg) o[ht][reg] *= al[reg];

        // P -> LDS (per-wave private region; wave-internal transpose)
#pragma unroll
        for (int nt = 0; nt < 4; ++nt)
#pragma unroll
            for (int reg = 0; reg < 4; ++reg)
                P_lds[wave][4 * lg + reg][lr + 16 * nt] = f2bf(s[nt][reg]);

        __asm__ volatile("s_waitcnt lgkmcnt(0)" ::: "memory");
        __builtin_amdgcn_sched_barrier(0);

        bf16x8 ap[2];
#pragma unroll
        for (int kk = 0; kk < 2; ++kk)
            ap[kk] = *reinterpret_cast<const bf16x8*>(&P_lds[wave][lr][kk * 32 + lg * 8]);

        // O += P V   (B-operand from transposed V: contiguous loads)
#pragma unroll
        for (int ht = 0; ht < 4; ++ht) {
#pragma unroll
            for (int kk = 0; kk < 2; ++kk) {
                bf16x8 bv = ld_bf8(Vb + (size_t)(lr + 16 * ht) * 4096 + kv0 + kk * 32 + lg * 8);
                o[ht] = __builtin_amdgcn_mfma_f32_16x16x32_bf16(ap[kk], bv, o[ht], 0, 0, 0);
            }
        }
        __asm__ volatile("" ::: "memory");
    }

    if (final_out) {
#pragma unroll
        for (int reg = 0; reg < 4; ++reg) l_run[reg] = 1.0f / l_run[reg];
#pragma unroll
        for (int ht = 0; ht < 4; ++ht)
#pragma unroll
            for (int reg = 0; reg < 4; ++reg)
                out[(size_t)(b * 4096 + qr0 + 4 * lg + reg) * 64 + lr + 16 * ht] =
                    o[ht][reg] * l_run[reg];
    } else {
        const int base = (ti * SPLIT + c) * 16;
#pragma unroll
        for (int ht = 0; ht < 4; ++ht)
#pragma unroll
            for (int reg = 0; reg < 4; ++reg)
                Opart[(size_t)(base + 4 * lg + reg) * 64 + lr + 16 * ht] = o[ht][reg];
        if (lr == 0) {
#pragma unroll
            for (int reg = 0; reg < 4; ++reg) {
                Mpart[base + 4 * lg + reg] = m_run[reg];
                Lpart[base + 4 * lg + reg] = l_run[reg];
            }
        }
    }
}

// ---------------------------------------------------------------------------
// Kernel 4: merge partials.  One thread per output element (t_glob, h).
// ---------------------------------------------------------------------------
__global__ __launch_bounds__(256) void merge_kernel(const float* __restrict__ Opart,
                                                    const float* __restrict__ Mpart,
                                                    const float* __restrict__ Lpart,
                                                    float* __restrict__ out,
                                                    int SPLIT, int CT) {
    const int idx = blockIdx.x * 256 + threadIdx.x;    // < 1048576
    const int h = idx & 63;
    const int tg = idx >> 6;                            // global row, < 16384
    const int ti = tg >> 4, row = tg & 15;
    const int qi = ti & 255;
    const int nkv = (qi >> 2) + 1;
    int nc = (nkv + CT - 1) / CT;
    if (nc > SPLIT) nc = SPLIT;

    const float L2E = 1.4426950408889634f;
    float M = -3.0e38f;
    for (int c = 0; c < nc; ++c)
        M = fmaxf(M, Mpart[(ti * SPLIT + c) * 16 + row]);
    float L = 0.f, acc = 0.f;
    for (int c = 0; c < nc; ++c) {
        const int base = (ti * SPLIT + c) * 16 + row;
        float w = exp2f((Mpart[base] - M) * L2E);
        L += w * Lpart[base];
        acc += w * Opart[(size_t)base * 64 + h];
    }
    out[(size_t)tg * 64 + h] = acc / L;
}

// ---------------------------------------------------------------------------
extern "C" void kernel_launch(void* const* d_in, const int* in_sizes, int n_in,
                              void* d_out, int out_size, void* d_ws, size_t ws_size,
                              hipStream_t stream) {
    const float* x  = (const float*)d_in[0];
    const float* Wq = (const float*)d_in[1];
    const float* Wk = (const float*)d_in[2];
    const float* Wv = (const float*)d_in[3];
    float* out = (float*)d_out;

    char* ws = (char*)d_ws;
    u16* Qw  = (u16*)(ws);                                 // 2 MiB
    u16* Kw  = (u16*)(ws + (size_t)2 * 1024 * 1024);       // 2 MiB
    u16* Vtw = (u16*)(ws + (size_t)4 * 1024 * 1024);       // 2 MiB
    u16* Wt  = (u16*)(ws + (size_t)6 * 1024 * 1024);       // 96 KiB

    // KV-split factor chosen by workspace size: need 8MB + SPLIT*(4MB+128KB)
    int SPLIT = 8;
    while (SPLIT > 1 &&
           (size_t)8 * 1024 * 1024 + (size_t)SPLIT * (4 * 1024 * 1024 + 128 * 1024) > ws_size)
        SPLIT >>= 1;
    const int CT = 64 / SPLIT;   // kv-tiles (of 64 keys) per chunk

    float* Opart = (float*)(ws + (size_t)8 * 1024 * 1024);
    float* Mpart = (float*)(ws + (size_t)8 * 1024 * 1024 + (size_t)SPLIT * 4 * 1024 * 1024);
    float* Lpart = Mpart + (size_t)SPLIT * 16384;

    wconv_kernel<<<384, 256, 0, stream>>>(Wq, Wk, Wv, Wt);
    proj_kernel<<<768, 256, 0, stream>>>(x, Wt, Qw, Kw, Vtw);

    const int final_out = (SPLIT == 1) ? 1 : 0;
    attn_part_kernel<<<256 * SPLIT, 256, 0, stream>>>(Qw, Kw, Vtw, Opart, Mpart, Lpart,
                                                      out, SPLIT, CT, final_out);
    if (!final_out)
        merge_kernel<<<4096, 256, 0, stream>>>(Opart, Mpart, Lpart, out, SPLIT, CT);
}